// Round 21
// baseline (128.036 us; speedup 1.0000x reference)
//
#include <hip/hip_runtime.h>
#include <hip/hip_bf16.h>

#define N_WORD  30000
#define N_TOPIC 512
#define N_DOC   10000
#define E_WT    262144
#define E_WD    262144
#define E_TD    131072
#define DIM     256
#define WT_BINS 16                      // src bin = src >> 11 (0..14 used)
#define SB_WT   (N_TOPIC * WT_BINS)     // 8192 sub-buckets
#define CAP_WT  96                      // mean 32,  +11 sigma
#define CAP_WD  72                      // mean 26.2, +8 sigma
#define CAP_TD  48                      // mean 13.1, +9 sigma
#define CSTRIDE 16                      // counters padded to 64B lines

typedef __attribute__((ext_vector_type(8))) short bf16x8;
typedef __attribute__((ext_vector_type(4))) float f32x4;
typedef __attribute__((ext_vector_type(2))) int int2v;
typedef __attribute__((ext_vector_type(4))) int int4v;

__device__ __forceinline__ short f2bf(float f) {
    __hip_bfloat16 h = __float2bfloat16(f);   // RNE
    short s;
    __builtin_memcpy(&s, &h, 2);
    return s;
}
// 16B (4 dwords = 8 bf16) accumulate: 2 bitops + 2 fma per dword
__device__ __forceinline__ void acc8(float* a, int4v d, float w) {
    #pragma unroll
    for (int k = 0; k < 4; ++k) {
        union { unsigned int u; float f; } lo, hi;
        lo.u = ((unsigned int)d[k]) << 16;
        hi.u = ((unsigned int)d[k]) & 0xffff0000u;
        a[2 * k]     += lo.f * w;
        a[2 * k + 1] += hi.f * w;
    }
}

// ====== k1: ILP-4 capacity-bucket scatter (line-padded counters) + casts ======
#define WT_SBLK 256
#define WD_SBLK 256
#define TD_SBLK 128
#define SCATTER_BLOCKS (WT_SBLK + WD_SBLK + TD_SBLK)    // 640
#define FWCAST_BLOCKS 3750          // 30000*256/8/256
#define FTCAST_BLOCKS 64            // 512*256/8/256
#define WCAST_BLOCKS  96            // 3*8192/256
#define SC_BLOCKS (SCATTER_BLOCKS + FWCAST_BLOCKS + FTCAST_BLOCKS + WCAST_BLOCKS)  // 4550

__global__ __launch_bounds__(256) void scatter_cast(
    const int* __restrict__ wt_src, const int* __restrict__ wt_dst, const float* __restrict__ w_wt,
    const int* __restrict__ wd_src, const int* __restrict__ wd_dst, const float* __restrict__ w_wd,
    const int* __restrict__ td_src, const int* __restrict__ td_dst, const float* __restrict__ w_td,
    int* __restrict__ cur_wt, int* __restrict__ cur_wd, int* __restrict__ cur_td,
    int2v* __restrict__ pk_wt, int2v* __restrict__ pk_wd, int2v* __restrict__ pk_td,
    const float* __restrict__ feat_word, const float* __restrict__ feat_topic,
    const float* __restrict__ Wt, const float* __restrict__ Wd, const float* __restrict__ Wtd,
    __hip_bfloat16* __restrict__ fw, __hip_bfloat16* __restrict__ ft,
    __hip_bfloat16* __restrict__ wbt, __hip_bfloat16* __restrict__ wbd,
    __hip_bfloat16* __restrict__ wbtd)
{
    int b = blockIdx.x;
    if (b < WT_SBLK) {              // wt -> (node*16 + srcbin) sub-buckets
        int e0 = b * 1024 + (int)threadIdx.x;
        int s[4], sb[4], pos[4];
        float wv[4];
        #pragma unroll
        for (int k = 0; k < 4; ++k) {
            int e = e0 + k * 256;
            s[k] = wt_src[e];
            sb[k] = wt_dst[e] * WT_BINS + (s[k] >> 11);
            wv[k] = w_wt[e];
        }
        #pragma unroll
        for (int k = 0; k < 4; ++k) pos[k] = atomicAdd(&cur_wt[sb[k] * CSTRIDE], 1);
        #pragma unroll
        for (int k = 0; k < 4; ++k)
            if (pos[k] < CAP_WT) {
                int2v p; p.x = s[k]; p.y = __float_as_int(wv[k]);
                pk_wt[(size_t)sb[k] * CAP_WT + pos[k]] = p;
            }
        return;
    }
    if (b < WT_SBLK + WD_SBLK) {    // wd -> per-doc buckets
        int e0 = (b - WT_SBLK) * 1024 + (int)threadIdx.x;
        int s[4], d[4], pos[4];
        float wv[4];
        #pragma unroll
        for (int k = 0; k < 4; ++k) {
            int e = e0 + k * 256;
            s[k] = wd_src[e];
            d[k] = wd_dst[e];
            wv[k] = w_wd[e];
        }
        #pragma unroll
        for (int k = 0; k < 4; ++k) pos[k] = atomicAdd(&cur_wd[d[k] * CSTRIDE], 1);
        #pragma unroll
        for (int k = 0; k < 4; ++k)
            if (pos[k] < CAP_WD) {
                int2v p; p.x = s[k]; p.y = __float_as_int(wv[k]);
                pk_wd[(size_t)d[k] * CAP_WD + pos[k]] = p;
            }
        return;
    }
    if (b < SCATTER_BLOCKS) {       // td
        int e0 = (b - WT_SBLK - WD_SBLK) * 1024 + (int)threadIdx.x;
        int s[4], d[4], pos[4];
        float wv[4];
        #pragma unroll
        for (int k = 0; k < 4; ++k) {
            int e = e0 + k * 256;
            s[k] = td_src[e];
            d[k] = td_dst[e];
            wv[k] = w_td[e];
        }
        #pragma unroll
        for (int k = 0; k < 4; ++k) pos[k] = atomicAdd(&cur_td[d[k] * CSTRIDE], 1);
        #pragma unroll
        for (int k = 0; k < 4; ++k)
            if (pos[k] < CAP_TD) {
                int2v p; p.x = s[k]; p.y = __float_as_int(wv[k]);
                pk_td[(size_t)d[k] * CAP_TD + pos[k]] = p;
            }
        return;
    }
    // ---- cast sections: 8 elems/thread f32 -> bf16 ----
    const float* src;
    unsigned short* dst;
    int local;
    int cb = b - SCATTER_BLOCKS;
    if (cb < FWCAST_BLOCKS) { src = feat_word; local = cb * 256 + (int)threadIdx.x; dst = (unsigned short*)fw; }
    else if (cb < FWCAST_BLOCKS + FTCAST_BLOCKS) {
        src = feat_topic; local = (cb - FWCAST_BLOCKS) * 256 + (int)threadIdx.x; dst = (unsigned short*)ft;
    } else {
        int i = (cb - FWCAST_BLOCKS - FTCAST_BLOCKS) * 256 + (int)threadIdx.x;
        if (i < 8192) { src = Wt; local = i; dst = (unsigned short*)wbt; }
        else if (i < 16384) { src = Wd; local = i - 8192; dst = (unsigned short*)wbd; }
        else { src = Wtd; local = i - 16384; dst = (unsigned short*)wbtd; }
    }
    f32x4 a = *reinterpret_cast<const f32x4*>(src + (size_t)local * 8);
    f32x4 c = *reinterpret_cast<const f32x4*>(src + (size_t)local * 8 + 4);
    bf16x8 r;
    r[0] = f2bf(a[0]); r[1] = f2bf(a[1]); r[2] = f2bf(a[2]); r[3] = f2bf(a[3]);
    r[4] = f2bf(c[0]); r[5] = f2bf(c[1]); r[6] = f2bf(c[2]); r[7] = f2bf(c[3]);
    *reinterpret_cast<bf16x8*>(dst + (size_t)local * 8) = r;
}

// ====== k2: paired-row gather (16B/lane, 8B payload) + word copy ======
#define GATHER_BLOCKS (SB_WT / 4 + 2 * N_DOC / 4)   // 2048 + 5000 = 7048
#define COPY_BLOCKS 3750
#define GC_BLOCKS (GATHER_BLOCKS + COPY_BLOCKS)     // 10798
__global__ __launch_bounds__(256) void gather_all(
    const __hip_bfloat16* __restrict__ fw, const __hip_bfloat16* __restrict__ ft,
    const int2v* __restrict__ pk_wt, const int* __restrict__ cur_wt,
    const int2v* __restrict__ pk_wd, const int* __restrict__ cur_wd,
    const int2v* __restrict__ pk_td, const int* __restrict__ cur_td,
    float* __restrict__ part, float* __restrict__ part_sumw,
    __hip_bfloat16* __restrict__ agg_wd, float* __restrict__ mw_wd,
    __hip_bfloat16* __restrict__ agg_td, float* __restrict__ mw_td,
    const float* __restrict__ feat_word, float* __restrict__ out_word)
{
    int bb = blockIdx.x;
    int wv = threadIdx.x >> 6;
    int lane = threadIdx.x & 63;
    int l = lane & 31, hi = lane >> 5;

    if (bb >= GATHER_BLOCKS) {      // word passthrough copy: 8 f32/thread
        int i = (bb - GATHER_BLOCKS) * 256 + (int)threadIdx.x;
        f32x4 a = *reinterpret_cast<const f32x4*>(feat_word + (size_t)i * 8);
        f32x4 c = *reinterpret_cast<const f32x4*>(feat_word + (size_t)i * 8 + 4);
        *reinterpret_cast<f32x4*>(out_word + (size_t)i * 8) = a;
        *reinterpret_cast<f32x4*>(out_word + (size_t)i * 8 + 4) = c;
        return;
    }

    const int2v* pk;
    const unsigned short* T;
    int cnt, deg = 0;
    bool is_wt = bb < SB_WT / 4;
    int node, chunk = 0;
    __hip_bfloat16* agg = nullptr;
    float* mw = nullptr;

    if (is_wt) {
        // wt: chunk == srcbin; same-chunk blocks co-resident per XCD (fw slice ~1MB)
        int xcd = bb & 7;
        int idx = bb >> 3;                  // 0..255
        chunk = (idx & 1) * 8 + xcd;        // 0..15
        node = (idx >> 1) * 4 + wv;         // 0..511
        int base = node * WT_BINS + chunk;
        cnt = cur_wt[base * CSTRIDE]; if (cnt > CAP_WT) cnt = CAP_WT;
        pk = pk_wt + (size_t)base * CAP_WT;
        T = (const unsigned short*)fw;
    } else {
        int w2 = (bb - SB_WT / 4) * 4 + wv; // 0..19999
        int rel = w2 >= N_DOC;
        node = rel ? w2 - N_DOC : w2;
        T = (const unsigned short*)(rel ? ft : fw);
        const int2v* pkb = rel ? pk_td : pk_wd;
        const int* cur = rel ? cur_td : cur_wd;
        const int cap = rel ? CAP_TD : CAP_WD;
        agg = rel ? agg_td : agg_wd;
        mw = rel ? mw_td : mw_wd;
        deg = cur[node * CSTRIDE];
        cnt = deg > cap ? cap : deg;
        pk = pkb + (size_t)node * cap;
    }

    float acc[8] = {0.f, 0.f, 0.f, 0.f, 0.f, 0.f, 0.f, 0.f};
    float sw = 0.f;
    int j = 0;
    for (; j + 8 <= cnt; j += 8) {          // 4 pairs per iteration
        int2v p[8];
        #pragma unroll
        for (int k = 0; k < 8; ++k) p[k] = pk[j + k];
        int4v v[4];
        #pragma unroll
        for (int q = 0; q < 4; ++q) {
            int r = hi ? p[2 * q + 1].x : p[2 * q].x;
            v[q] = *reinterpret_cast<const int4v*>(T + (size_t)r * DIM + l * 8);
        }
        #pragma unroll
        for (int q = 0; q < 4; ++q) {
            float w = __int_as_float(hi ? p[2 * q + 1].y : p[2 * q].y);
            acc8(acc, v[q], w);
            sw += w;
        }
    }
    for (; j + 2 <= cnt; j += 2) {          // single pair
        int2v p0 = pk[j], p1 = pk[j + 1];
        int r = hi ? p1.x : p0.x;
        float w = __int_as_float(hi ? p1.y : p0.y);
        int4v v = *reinterpret_cast<const int4v*>(T + (size_t)r * DIM + l * 8);
        acc8(acc, v, w);
        sw += w;
    }
    if (j < cnt) {                          // odd tail: hi half mirrors with w=0
        int2v p0 = pk[j];
        float w = hi ? 0.f : __int_as_float(p0.y);
        int4v v = *reinterpret_cast<const int4v*>(T + (size_t)p0.x * DIM + l * 8);
        acc8(acc, v, w);
        sw += w;
    }
    // fold the two 32-lane halves
    #pragma unroll
    for (int k = 0; k < 8; ++k) acc[k] += __shfl_xor(acc[k], 32, 64);
    sw += __shfl_xor(sw, 32, 64);

    if (is_wt) {
        if (hi == 0) {
            float* pdst = part + ((size_t)chunk * N_TOPIC + node) * DIM + l * 8;
            f32x4 r0 = {acc[0], acc[1], acc[2], acc[3]};
            f32x4 r1 = {acc[4], acc[5], acc[6], acc[7]};
            *reinterpret_cast<f32x4*>(pdst) = r0;
            *reinterpret_cast<f32x4*>(pdst + 4) = r1;
        }
        if (lane == 0) part_sumw[chunk * N_TOPIC + node] = sw;
    } else {
        float inv = 1.f / (float)(deg > 1 ? deg : 1);
        if (hi == 0) {
            int4v r;
            #pragma unroll
            for (int k = 0; k < 4; ++k) {
                unsigned int lo = (unsigned short)f2bf(acc[2 * k] * inv);
                unsigned int hb = (unsigned short)f2bf(acc[2 * k + 1] * inv);
                r[k] = (int)((hb << 16) | lo);
            }
            *reinterpret_cast<int4v*>((unsigned short*)agg + (size_t)node * DIM + l * 8) = r;
        }
        if (lane == 0) mw[node] = sw * inv;
    }
}

// ====== k3: gemm + fused topic reduction; doc strips XCD-partitioned ======
// Explicit full load-hoist + launch_bounds(256,1): keep all 32 tile loads in
// flight (theory: VGPR=60 forced load serialization -> 44us latency-bound).
#define DOC_STRIPS 625              // 10000/16
#define STRIPS_PER_XCD 79           // ceil(625/8)
#define DOC_BLOCKS (8 * STRIPS_PER_XCD * 4)     // 2528 (4 cgroups/strip)
#define GEMM_BLOCKS (32 + DOC_BLOCKS)           // 2560

__global__ __launch_bounds__(256, 1) void gemm_all(
    const float* __restrict__ part, const float* __restrict__ part_sumw,
    const int* __restrict__ cur_wt,
    const __hip_bfloat16* __restrict__ wbt, const float* __restrict__ bt,
    const __hip_bfloat16* __restrict__ agg_wd, const __hip_bfloat16* __restrict__ wbd,
    const float* __restrict__ bd, const float* __restrict__ mw_d1,
    const __hip_bfloat16* __restrict__ agg_td, const __hip_bfloat16* __restrict__ wbtd,
    const float* __restrict__ btd, const float* __restrict__ mw_d2,
    float* __restrict__ out_topic, float* __restrict__ out_doc)
{
    int lane = threadIdx.x & 63;
    int wv = threadIdx.x >> 6;
    int lr = lane & 15, kh = lane >> 4;

    if (blockIdx.x < 32) {
        __shared__ unsigned short A[16][DIM + 8];   // +16B pad -> 2-way banks only
        __shared__ float mwv[16];
        __shared__ float invv[16];
        int rt = blockIdx.x;
        int t = threadIdx.x;
        if (t < 16) {
            int node = rt * 16 + t;
            int d = 0;
            float swt = 0.f;
            #pragma unroll
            for (int c = 0; c < WT_BINS; ++c) {
                int v = cur_wt[(node * WT_BINS + c) * CSTRIDE];
                d += v > CAP_WT ? CAP_WT : v;
                swt += part_sumw[c * N_TOPIC + node];
            }
            float inv = 1.f / (float)(d > 1 ? d : 1);
            invv[t] = inv;
            mwv[t] = swt * inv;
        }
        __syncthreads();
        for (int i = t; i < 16 * DIM; i += 256) {
            int n = i >> 8, d = i & 255;
            int node = rt * 16 + n;
            float s = 0.f;
            #pragma unroll
            for (int c = 0; c < WT_BINS; ++c)
                s += part[((size_t)c * N_TOPIC + node) * DIM + d];
            A[n][d] = (unsigned short)f2bf(s * invv[n]);
        }
        __syncthreads();
        #pragma unroll
        for (int q = 0; q < 4; ++q) {
            int ct = wv * 4 + q;
            f32x4 acc = {0.f, 0.f, 0.f, 0.f};
            const unsigned short* Ab = &A[lr][kh * 8];
            const unsigned short* Wb = (const unsigned short*)wbt + (size_t)(ct * 16 + lr) * DIM + kh * 8;
            #pragma unroll
            for (int kk = 0; kk < 8; ++kk) {
                bf16x8 a = *reinterpret_cast<const bf16x8*>(Ab + kk * 32);
                bf16x8 b = *reinterpret_cast<const bf16x8*>(Wb + kk * 32);
                acc = __builtin_amdgcn_mfma_f32_16x16x32_bf16(a, b, acc, 0, 0, 0);
            }
            float bb = bt[ct * 16 + lr];
            #pragma unroll
            for (int j = 0; j < 4; ++j) {
                int n = kh * 4 + j;
                out_topic[(size_t)(rt * 16 + n) * DIM + ct * 16 + lr] = acc[j] + bb * mwv[n];
            }
        }
        return;
    }

    // ---- doc tiles: rt strips partitioned by XCD; ALL loads hoisted ----
    int b = blockIdx.x - 32;
    int xcd = b & 7;
    int idx = b >> 3;                   // 0..315
    int rt = xcd * STRIPS_PER_XCD + (idx >> 2);
    if (rt >= DOC_STRIPS) return;
    int ct = (idx & 3) * 4 + wv;        // cgroup*4 + wave

    const unsigned short* A1 = (const unsigned short*)agg_wd + (size_t)(rt * 16 + lr) * DIM + kh * 8;
    const unsigned short* A2 = (const unsigned short*)agg_td + (size_t)(rt * 16 + lr) * DIM + kh * 8;
    const unsigned short* W1 = (const unsigned short*)wbd  + (size_t)(ct * 16 + lr) * DIM + kh * 8;
    const unsigned short* W2 = (const unsigned short*)wbtd + (size_t)(ct * 16 + lr) * DIM + kh * 8;

    bf16x8 a1[8], a2[8], w1[8], w2[8];
    #pragma unroll
    for (int kk = 0; kk < 8; ++kk) {
        a1[kk] = *reinterpret_cast<const bf16x8*>(A1 + kk * 32);
        a2[kk] = *reinterpret_cast<const bf16x8*>(A2 + kk * 32);
        w1[kk] = *reinterpret_cast<const bf16x8*>(W1 + kk * 32);
        w2[kk] = *reinterpret_cast<const bf16x8*>(W2 + kk * 32);
    }
    f32x4 acc = {0.f, 0.f, 0.f, 0.f};
    #pragma unroll
    for (int kk = 0; kk < 8; ++kk)
        acc = __builtin_amdgcn_mfma_f32_16x16x32_bf16(a1[kk], w1[kk], acc, 0, 0, 0);
    #pragma unroll
    for (int kk = 0; kk < 8; ++kk)
        acc = __builtin_amdgcn_mfma_f32_16x16x32_bf16(a2[kk], w2[kk], acc, 0, 0, 0);

    float bb1 = bd[ct * 16 + lr];
    float bb2 = btd[ct * 16 + lr];
    #pragma unroll
    for (int j = 0; j < 4; ++j) {
        int row = rt * 16 + kh * 4 + j;
        float v = acc[j] + bb1 * mw_d1[row] + bb2 * mw_d2[row];
        out_doc[(size_t)row * DIM + ct * 16 + lr] = fmaxf(v, 0.f);
    }
}

extern "C" void kernel_launch(void* const* d_in, const int* in_sizes, int n_in,
                              void* d_out, int out_size, void* d_ws, size_t ws_size,
                              hipStream_t stream)
{
    const float* feat_word  = (const float*)d_in[0];
    const float* feat_topic = (const float*)d_in[1];
    /* feat_doc (d_in[2]) unused by the reference output */
    const int* wt_src = (const int*)d_in[3];
    const int* wt_dst = (const int*)d_in[4];
    const int* wd_src = (const int*)d_in[5];
    const int* wd_dst = (const int*)d_in[6];
    const int* td_src = (const int*)d_in[7];
    const int* td_dst = (const int*)d_in[8];
    const float* w_wt = (const float*)d_in[9];
    const float* w_wd = (const float*)d_in[10];
    const float* w_td = (const float*)d_in[11];
    const float* Wt   = (const float*)d_in[12];
    const float* bt   = (const float*)d_in[13];
    const float* Wd   = (const float*)d_in[14];
    const float* bd   = (const float*)d_in[15];
    const float* Wtd  = (const float*)d_in[16];
    const float* btd  = (const float*)d_in[17];

    char* ws = (char*)d_ws;
    // Workspace layout (bytes), ~52.5 MB total:
    __hip_bfloat16* fw     = (__hip_bfloat16*)(ws + 0);         // 15,360,000
    __hip_bfloat16* ft     = (__hip_bfloat16*)(ws + 15360000);  // 262,144
    __hip_bfloat16* wbt    = (__hip_bfloat16*)(ws + 15622144);  // 131,072
    __hip_bfloat16* wbd    = (__hip_bfloat16*)(ws + 15753216);  // 131,072
    __hip_bfloat16* wbtd   = (__hip_bfloat16*)(ws + 15884288);  // 131,072 -> 16,015,360
    __hip_bfloat16* agg_wd = (__hip_bfloat16*)(ws + 16015360);  // 5,120,000 (bf16)
    __hip_bfloat16* agg_td = (__hip_bfloat16*)(ws + 21135360);  // 5,120,000 (bf16)
    float* part      = (float*)(ws + 26255360);                 // 16*512*256*4 = 8,388,608
    float* part_sumw = (float*)(ws + 34643968);                 // 32,768
    float* mw_wd     = (float*)(ws + 34676736);                 // 40,000
    float* mw_td     = (float*)(ws + 34716736);                 // 40,000 -> 34,756,736
    // line-padded allocator counters (1 counter per 64B line):
    int* cur_wt = (int*)(ws + 34756736);                        // 8192*64  = 524,288
    int* cur_wd = (int*)(ws + 35281024);                        // 10000*64 = 640,000
    int* cur_td = (int*)(ws + 35921024);                        // 10000*64 = 640,000 -> 36,561,024
    int2v* pk_wt = (int2v*)(ws + 36561024);                     // 8192*96*8  = 6,291,456
    int2v* pk_wd = (int2v*)(ws + 42852480);                     // 10000*72*8 = 5,760,000
    int2v* pk_td = (int2v*)(ws + 48612480);                     // 10000*48*8 = 3,840,000
    //                                                          // -> 52,452,480

    float* out = (float*)d_out;
    float* out_topic = out + (size_t)N_WORD * DIM;
    float* out_doc   = out + (size_t)(N_WORD + N_TOPIC) * DIM;

    // zero line-padded bucket allocators (contiguous 1,804,288 B)
    hipMemsetAsync(ws + 34756736, 0, 1804288, stream);

    // k1: ILP-4 capacity-bucket scatter + bf16 casts
    scatter_cast<<<SC_BLOCKS, 256, 0, stream>>>(
        wt_src, wt_dst, w_wt, wd_src, wd_dst, w_wd, td_src, td_dst, w_td,
        cur_wt, cur_wd, cur_td, pk_wt, pk_wd, pk_td,
        feat_word, feat_topic, Wt, Wd, Wtd, fw, ft, wbt, wbd, wbtd);

    // k2: paired-row gathers + word passthrough copy
    gather_all<<<GC_BLOCKS, 256, 0, stream>>>(
        fw, ft,
        pk_wt, cur_wt,
        pk_wd, cur_wd,
        pk_td, cur_td,
        part, part_sumw, agg_wd, mw_wd, agg_td, mw_td,
        feat_word, out);

    // k3: gemm (full load-hoist, launch_bounds(256,1)); doc strips XCD-partitioned
    gemm_all<<<GEMM_BLOCKS, 256, 0, stream>>>(
        part, part_sumw, cur_wt,
        wbt, bt,
        agg_wd, wbd, bd, mw_wd,
        agg_td, wbtd, btd, mw_td,
        out_topic, out_doc);
}

// Round 22
// 108.943 us; speedup vs baseline: 1.1753x; 1.1753x over previous
//
#include <hip/hip_runtime.h>
#include <hip/hip_bf16.h>

#define N_WORD  30000
#define N_TOPIC 512
#define N_DOC   10000
#define E_WT    262144
#define E_WD    262144
#define E_TD    131072
#define DIM     256
#define WT_BINS 16                      // src bin = src >> 11 (0..14 used)
#define SB_WT   (N_TOPIC * WT_BINS)     // 8192 sub-buckets
#define CAP_WT  96                      // mean 32,  +11 sigma
#define CAP_WD  72                      // mean 26.2, +8 sigma
#define CAP_TD  48                      // mean 13.1, +9 sigma
#define CSTRIDE 16                      // counters padded to 64B lines

typedef __attribute__((ext_vector_type(8))) short bf16x8;
typedef __attribute__((ext_vector_type(4))) float f32x4;
typedef __attribute__((ext_vector_type(2))) int int2v;
typedef __attribute__((ext_vector_type(4))) int int4v;

__device__ __forceinline__ short f2bf(float f) {
    __hip_bfloat16 h = __float2bfloat16(f);   // RNE
    short s;
    __builtin_memcpy(&s, &h, 2);
    return s;
}
// 16B (4 dwords = 8 bf16) accumulate: 2 bitops + 2 fma per dword
__device__ __forceinline__ void acc8(float* a, int4v d, float w) {
    #pragma unroll
    for (int k = 0; k < 4; ++k) {
        union { unsigned int u; float f; } lo, hi;
        lo.u = ((unsigned int)d[k]) << 16;
        hi.u = ((unsigned int)d[k]) & 0xffff0000u;
        a[2 * k]     += lo.f * w;
        a[2 * k + 1] += hi.f * w;
    }
}

// ====== k1: ILP-4 capacity-bucket scatter (line-padded counters) + casts ======
#define WT_SBLK 256
#define WD_SBLK 256
#define TD_SBLK 128
#define SCATTER_BLOCKS (WT_SBLK + WD_SBLK + TD_SBLK)    // 640
#define FWCAST_BLOCKS 3750          // 30000*256/8/256
#define FTCAST_BLOCKS 64            // 512*256/8/256
#define WCAST_BLOCKS  96            // 3*8192/256
#define SC_BLOCKS (SCATTER_BLOCKS + FWCAST_BLOCKS + FTCAST_BLOCKS + WCAST_BLOCKS)  // 4550

__global__ __launch_bounds__(256) void scatter_cast(
    const int* __restrict__ wt_src, const int* __restrict__ wt_dst, const float* __restrict__ w_wt,
    const int* __restrict__ wd_src, const int* __restrict__ wd_dst, const float* __restrict__ w_wd,
    const int* __restrict__ td_src, const int* __restrict__ td_dst, const float* __restrict__ w_td,
    int* __restrict__ cur_wt, int* __restrict__ cur_wd, int* __restrict__ cur_td,
    int2v* __restrict__ pk_wt, int2v* __restrict__ pk_wd, int2v* __restrict__ pk_td,
    const float* __restrict__ feat_word, const float* __restrict__ feat_topic,
    const float* __restrict__ Wt, const float* __restrict__ Wd, const float* __restrict__ Wtd,
    __hip_bfloat16* __restrict__ fw, __hip_bfloat16* __restrict__ ft,
    __hip_bfloat16* __restrict__ wbt, __hip_bfloat16* __restrict__ wbd,
    __hip_bfloat16* __restrict__ wbtd)
{
    int b = blockIdx.x;
    if (b < WT_SBLK) {              // wt -> (node*16 + srcbin) sub-buckets
        int e0 = b * 1024 + (int)threadIdx.x;
        int s[4], sb[4], pos[4];
        float wv[4];
        #pragma unroll
        for (int k = 0; k < 4; ++k) {
            int e = e0 + k * 256;
            s[k] = wt_src[e];
            sb[k] = wt_dst[e] * WT_BINS + (s[k] >> 11);
            wv[k] = w_wt[e];
        }
        #pragma unroll
        for (int k = 0; k < 4; ++k) pos[k] = atomicAdd(&cur_wt[sb[k] * CSTRIDE], 1);
        #pragma unroll
        for (int k = 0; k < 4; ++k)
            if (pos[k] < CAP_WT) {
                int2v p; p.x = s[k]; p.y = __float_as_int(wv[k]);
                pk_wt[(size_t)sb[k] * CAP_WT + pos[k]] = p;
            }
        return;
    }
    if (b < WT_SBLK + WD_SBLK) {    // wd -> per-doc buckets
        int e0 = (b - WT_SBLK) * 1024 + (int)threadIdx.x;
        int s[4], d[4], pos[4];
        float wv[4];
        #pragma unroll
        for (int k = 0; k < 4; ++k) {
            int e = e0 + k * 256;
            s[k] = wd_src[e];
            d[k] = wd_dst[e];
            wv[k] = w_wd[e];
        }
        #pragma unroll
        for (int k = 0; k < 4; ++k) pos[k] = atomicAdd(&cur_wd[d[k] * CSTRIDE], 1);
        #pragma unroll
        for (int k = 0; k < 4; ++k)
            if (pos[k] < CAP_WD) {
                int2v p; p.x = s[k]; p.y = __float_as_int(wv[k]);
                pk_wd[(size_t)d[k] * CAP_WD + pos[k]] = p;
            }
        return;
    }
    if (b < SCATTER_BLOCKS) {       // td
        int e0 = (b - WT_SBLK - WD_SBLK) * 1024 + (int)threadIdx.x;
        int s[4], d[4], pos[4];
        float wv[4];
        #pragma unroll
        for (int k = 0; k < 4; ++k) {
            int e = e0 + k * 256;
            s[k] = td_src[e];
            d[k] = td_dst[e];
            wv[k] = w_td[e];
        }
        #pragma unroll
        for (int k = 0; k < 4; ++k) pos[k] = atomicAdd(&cur_td[d[k] * CSTRIDE], 1);
        #pragma unroll
        for (int k = 0; k < 4; ++k)
            if (pos[k] < CAP_TD) {
                int2v p; p.x = s[k]; p.y = __float_as_int(wv[k]);
                pk_td[(size_t)d[k] * CAP_TD + pos[k]] = p;
            }
        return;
    }
    // ---- cast sections: 8 elems/thread f32 -> bf16 ----
    const float* src;
    unsigned short* dst;
    int local;
    int cb = b - SCATTER_BLOCKS;
    if (cb < FWCAST_BLOCKS) { src = feat_word; local = cb * 256 + (int)threadIdx.x; dst = (unsigned short*)fw; }
    else if (cb < FWCAST_BLOCKS + FTCAST_BLOCKS) {
        src = feat_topic; local = (cb - FWCAST_BLOCKS) * 256 + (int)threadIdx.x; dst = (unsigned short*)ft;
    } else {
        int i = (cb - FWCAST_BLOCKS - FTCAST_BLOCKS) * 256 + (int)threadIdx.x;
        if (i < 8192) { src = Wt; local = i; dst = (unsigned short*)wbt; }
        else if (i < 16384) { src = Wd; local = i - 8192; dst = (unsigned short*)wbd; }
        else { src = Wtd; local = i - 16384; dst = (unsigned short*)wbtd; }
    }
    f32x4 a = *reinterpret_cast<const f32x4*>(src + (size_t)local * 8);
    f32x4 c = *reinterpret_cast<const f32x4*>(src + (size_t)local * 8 + 4);
    bf16x8 r;
    r[0] = f2bf(a[0]); r[1] = f2bf(a[1]); r[2] = f2bf(a[2]); r[3] = f2bf(a[3]);
    r[4] = f2bf(c[0]); r[5] = f2bf(c[1]); r[6] = f2bf(c[2]); r[7] = f2bf(c[3]);
    *reinterpret_cast<bf16x8*>(dst + (size_t)local * 8) = r;
}

// ====== k2: paired-row gather (16B/lane, 8B payload) + word copy ======
#define GATHER_BLOCKS (SB_WT / 4 + 2 * N_DOC / 4)   // 2048 + 5000 = 7048
#define COPY_BLOCKS 3750
#define GC_BLOCKS (GATHER_BLOCKS + COPY_BLOCKS)     // 10798
__global__ __launch_bounds__(256) void gather_all(
    const __hip_bfloat16* __restrict__ fw, const __hip_bfloat16* __restrict__ ft,
    const int2v* __restrict__ pk_wt, const int* __restrict__ cur_wt,
    const int2v* __restrict__ pk_wd, const int* __restrict__ cur_wd,
    const int2v* __restrict__ pk_td, const int* __restrict__ cur_td,
    float* __restrict__ part, float* __restrict__ part_sumw,
    __hip_bfloat16* __restrict__ agg_wd, float* __restrict__ mw_wd,
    __hip_bfloat16* __restrict__ agg_td, float* __restrict__ mw_td,
    const float* __restrict__ feat_word, float* __restrict__ out_word)
{
    int bb = blockIdx.x;
    int wv = threadIdx.x >> 6;
    int lane = threadIdx.x & 63;
    int l = lane & 31, hi = lane >> 5;

    if (bb >= GATHER_BLOCKS) {      // word passthrough copy: 8 f32/thread
        int i = (bb - GATHER_BLOCKS) * 256 + (int)threadIdx.x;
        f32x4 a = *reinterpret_cast<const f32x4*>(feat_word + (size_t)i * 8);
        f32x4 c = *reinterpret_cast<const f32x4*>(feat_word + (size_t)i * 8 + 4);
        *reinterpret_cast<f32x4*>(out_word + (size_t)i * 8) = a;
        *reinterpret_cast<f32x4*>(out_word + (size_t)i * 8 + 4) = c;
        return;
    }

    const int2v* pk;
    const unsigned short* T;
    int cnt, deg = 0;
    bool is_wt = bb < SB_WT / 4;
    int node, chunk = 0;
    __hip_bfloat16* agg = nullptr;
    float* mw = nullptr;

    if (is_wt) {
        // wt: chunk == srcbin; same-chunk blocks co-resident per XCD (fw slice ~1MB)
        int xcd = bb & 7;
        int idx = bb >> 3;                  // 0..255
        chunk = (idx & 1) * 8 + xcd;        // 0..15
        node = (idx >> 1) * 4 + wv;         // 0..511
        int base = node * WT_BINS + chunk;
        cnt = cur_wt[base * CSTRIDE]; if (cnt > CAP_WT) cnt = CAP_WT;
        pk = pk_wt + (size_t)base * CAP_WT;
        T = (const unsigned short*)fw;
    } else {
        int w2 = (bb - SB_WT / 4) * 4 + wv; // 0..19999
        int rel = w2 >= N_DOC;
        node = rel ? w2 - N_DOC : w2;
        T = (const unsigned short*)(rel ? ft : fw);
        const int2v* pkb = rel ? pk_td : pk_wd;
        const int* cur = rel ? cur_td : cur_wd;
        const int cap = rel ? CAP_TD : CAP_WD;
        agg = rel ? agg_td : agg_wd;
        mw = rel ? mw_td : mw_wd;
        deg = cur[node * CSTRIDE];
        cnt = deg > cap ? cap : deg;
        pk = pkb + (size_t)node * cap;
    }

    float acc[8] = {0.f, 0.f, 0.f, 0.f, 0.f, 0.f, 0.f, 0.f};
    float sw = 0.f;
    int j = 0;
    for (; j + 8 <= cnt; j += 8) {          // 4 pairs per iteration
        int2v p[8];
        #pragma unroll
        for (int k = 0; k < 8; ++k) p[k] = pk[j + k];
        int4v v[4];
        #pragma unroll
        for (int q = 0; q < 4; ++q) {
            int r = hi ? p[2 * q + 1].x : p[2 * q].x;
            v[q] = *reinterpret_cast<const int4v*>(T + (size_t)r * DIM + l * 8);
        }
        #pragma unroll
        for (int q = 0; q < 4; ++q) {
            float w = __int_as_float(hi ? p[2 * q + 1].y : p[2 * q].y);
            acc8(acc, v[q], w);
            sw += w;
        }
    }
    for (; j + 2 <= cnt; j += 2) {          // single pair
        int2v p0 = pk[j], p1 = pk[j + 1];
        int r = hi ? p1.x : p0.x;
        float w = __int_as_float(hi ? p1.y : p0.y);
        int4v v = *reinterpret_cast<const int4v*>(T + (size_t)r * DIM + l * 8);
        acc8(acc, v, w);
        sw += w;
    }
    if (j < cnt) {                          // odd tail: hi half mirrors with w=0
        int2v p0 = pk[j];
        float w = hi ? 0.f : __int_as_float(p0.y);
        int4v v = *reinterpret_cast<const int4v*>(T + (size_t)p0.x * DIM + l * 8);
        acc8(acc, v, w);
        sw += w;
    }
    // fold the two 32-lane halves
    #pragma unroll
    for (int k = 0; k < 8; ++k) acc[k] += __shfl_xor(acc[k], 32, 64);
    sw += __shfl_xor(sw, 32, 64);

    if (is_wt) {
        if (hi == 0) {
            float* pdst = part + ((size_t)chunk * N_TOPIC + node) * DIM + l * 8;
            f32x4 r0 = {acc[0], acc[1], acc[2], acc[3]};
            f32x4 r1 = {acc[4], acc[5], acc[6], acc[7]};
            *reinterpret_cast<f32x4*>(pdst) = r0;
            *reinterpret_cast<f32x4*>(pdst + 4) = r1;
        }
        if (lane == 0) part_sumw[chunk * N_TOPIC + node] = sw;
    } else {
        float inv = 1.f / (float)(deg > 1 ? deg : 1);
        if (hi == 0) {
            int4v r;
            #pragma unroll
            for (int k = 0; k < 4; ++k) {
                unsigned int lo = (unsigned short)f2bf(acc[2 * k] * inv);
                unsigned int hb = (unsigned short)f2bf(acc[2 * k + 1] * inv);
                r[k] = (int)((hb << 16) | lo);
            }
            *reinterpret_cast<int4v*>((unsigned short*)agg + (size_t)node * DIM + l * 8) = r;
        }
        if (lane == 0) mw[node] = sw * inv;
    }
}

// ====== k3: gemm; doc strips LDS-staged (A read ONCE per strip) ======
// blocks 0..31: topic strips | blocks 32..344: doc 32-row strips
#define DOC_BLOCKS 313              // 312 x 32 rows + 1 x 16 rows
#define GEMM_BLOCKS (32 + DOC_BLOCKS)   // 345
#define LROW (DIM + 8)              // padded LDS row (shorts): 2-way banks only

__global__ __launch_bounds__(256) void gemm_all(
    const float* __restrict__ part, const float* __restrict__ part_sumw,
    const int* __restrict__ cur_wt,
    const __hip_bfloat16* __restrict__ wbt, const float* __restrict__ bt,
    const __hip_bfloat16* __restrict__ agg_wd, const __hip_bfloat16* __restrict__ wbd,
    const float* __restrict__ bd, const float* __restrict__ mw_d1,
    const __hip_bfloat16* __restrict__ agg_td, const __hip_bfloat16* __restrict__ wbtd,
    const float* __restrict__ btd, const float* __restrict__ mw_d2,
    float* __restrict__ out_topic, float* __restrict__ out_doc)
{
    int lane = threadIdx.x & 63;
    int wv = threadIdx.x >> 6;
    int lr = lane & 15, kh = lane >> 4;
    int t = threadIdx.x;

    if (blockIdx.x < 32) {
        __shared__ unsigned short A[16][LROW];
        __shared__ float mwv[16];
        __shared__ float invv[16];
        int rt = blockIdx.x;
        if (t < 16) {
            int node = rt * 16 + t;
            int d = 0;
            float swt = 0.f;
            #pragma unroll
            for (int c = 0; c < WT_BINS; ++c) {
                int v = cur_wt[(node * WT_BINS + c) * CSTRIDE];
                d += v > CAP_WT ? CAP_WT : v;
                swt += part_sumw[c * N_TOPIC + node];
            }
            float inv = 1.f / (float)(d > 1 ? d : 1);
            invv[t] = inv;
            mwv[t] = swt * inv;
        }
        __syncthreads();
        for (int i = t; i < 16 * DIM; i += 256) {
            int n = i >> 8, d = i & 255;
            int node = rt * 16 + n;
            float s = 0.f;
            #pragma unroll
            for (int c = 0; c < WT_BINS; ++c)
                s += part[((size_t)c * N_TOPIC + node) * DIM + d];
            A[n][d] = (unsigned short)f2bf(s * invv[n]);
        }
        __syncthreads();
        #pragma unroll
        for (int q = 0; q < 4; ++q) {
            int ct = wv * 4 + q;
            f32x4 acc = {0.f, 0.f, 0.f, 0.f};
            const unsigned short* Ab = &A[lr][kh * 8];
            const unsigned short* Wb = (const unsigned short*)wbt + (size_t)(ct * 16 + lr) * DIM + kh * 8;
            #pragma unroll
            for (int kk = 0; kk < 8; ++kk) {
                bf16x8 a = *reinterpret_cast<const bf16x8*>(Ab + kk * 32);
                bf16x8 b = *reinterpret_cast<const bf16x8*>(Wb + kk * 32);
                acc = __builtin_amdgcn_mfma_f32_16x16x32_bf16(a, b, acc, 0, 0, 0);
            }
            float bb = bt[ct * 16 + lr];
            #pragma unroll
            for (int j = 0; j < 4; ++j) {
                int n = kh * 4 + j;
                out_topic[(size_t)(rt * 16 + n) * DIM + ct * 16 + lr] = acc[j] + bb * mwv[n];
            }
        }
        return;
    }

    // ---- doc strips: stage A (both rels) in LDS once, compute all 16 cts ----
    __shared__ unsigned short As[2][32][LROW];  // 33.8 KB
    int b = blockIdx.x - 32;        // 0..312
    int rb = b * 32;
    int nrows = N_DOC - rb; if (nrows > 32) nrows = 32;   // 32 or 16

    if (nrows == 32) {
        for (int i = t; i < 2 * 32 * 32; i += 256) {      // 16B chunks
            int rel = i >> 10;
            int rem = i & 1023;
            int row = rem >> 5;
            int c8 = rem & 31;
            const unsigned short* src =
                (const unsigned short*)(rel ? agg_td : agg_wd) + (size_t)(rb + row) * DIM + c8 * 8;
            *reinterpret_cast<bf16x8*>(&As[rel][row][c8 * 8]) =
                *reinterpret_cast<const bf16x8*>(src);
        }
    } else {
        for (int i = t; i < 2 * nrows * 32; i += 256) {
            int rel = i / (nrows * 32);
            int rem = i % (nrows * 32);
            int row = rem >> 5;
            int c8 = rem & 31;
            const unsigned short* src =
                (const unsigned short*)(rel ? agg_td : agg_wd) + (size_t)(rb + row) * DIM + c8 * 8;
            *reinterpret_cast<bf16x8*>(&As[rel][row][c8 * 8]) =
                *reinterpret_cast<const bf16x8*>(src);
        }
    }
    __syncthreads();

    int nsub = nrows >> 4;          // 2 or 1
    #pragma unroll
    for (int q = 0; q < 4; ++q) {
        int ct = wv * 4 + q;
        const unsigned short* W1 = (const unsigned short*)wbd  + (size_t)(ct * 16 + lr) * DIM + kh * 8;
        const unsigned short* W2 = (const unsigned short*)wbtd + (size_t)(ct * 16 + lr) * DIM + kh * 8;
        bf16x8 w1[8], w2[8];
        #pragma unroll
        for (int kk = 0; kk < 8; ++kk) {
            w1[kk] = *reinterpret_cast<const bf16x8*>(W1 + kk * 32);
            w2[kk] = *reinterpret_cast<const bf16x8*>(W2 + kk * 32);
        }
        float bb1 = bd[ct * 16 + lr];
        float bb2 = btd[ct * 16 + lr];
        for (int sub = 0; sub < nsub; ++sub) {
            f32x4 acc = {0.f, 0.f, 0.f, 0.f};
            const unsigned short* A1 = &As[0][sub * 16 + lr][kh * 8];
            const unsigned short* A2 = &As[1][sub * 16 + lr][kh * 8];
            #pragma unroll
            for (int kk = 0; kk < 8; ++kk)
                acc = __builtin_amdgcn_mfma_f32_16x16x32_bf16(
                    *reinterpret_cast<const bf16x8*>(A1 + kk * 32), w1[kk], acc, 0, 0, 0);
            #pragma unroll
            for (int kk = 0; kk < 8; ++kk)
                acc = __builtin_amdgcn_mfma_f32_16x16x32_bf16(
                    *reinterpret_cast<const bf16x8*>(A2 + kk * 32), w2[kk], acc, 0, 0, 0);
            #pragma unroll
            for (int j = 0; j < 4; ++j) {
                int row = rb + sub * 16 + kh * 4 + j;
                float v = acc[j] + bb1 * mw_d1[row] + bb2 * mw_d2[row];
                out_doc[(size_t)row * DIM + ct * 16 + lr] = fmaxf(v, 0.f);
            }
        }
    }
}

extern "C" void kernel_launch(void* const* d_in, const int* in_sizes, int n_in,
                              void* d_out, int out_size, void* d_ws, size_t ws_size,
                              hipStream_t stream)
{
    const float* feat_word  = (const float*)d_in[0];
    const float* feat_topic = (const float*)d_in[1];
    /* feat_doc (d_in[2]) unused by the reference output */
    const int* wt_src = (const int*)d_in[3];
    const int* wt_dst = (const int*)d_in[4];
    const int* wd_src = (const int*)d_in[5];
    const int* wd_dst = (const int*)d_in[6];
    const int* td_src = (const int*)d_in[7];
    const int* td_dst = (const int*)d_in[8];
    const float* w_wt = (const float*)d_in[9];
    const float* w_wd = (const float*)d_in[10];
    const float* w_td = (const float*)d_in[11];
    const float* Wt   = (const float*)d_in[12];
    const float* bt   = (const float*)d_in[13];
    const float* Wd   = (const float*)d_in[14];
    const float* bd   = (const float*)d_in[15];
    const float* Wtd  = (const float*)d_in[16];
    const float* btd  = (const float*)d_in[17];

    char* ws = (char*)d_ws;
    // Workspace layout (bytes), ~52.5 MB total:
    __hip_bfloat16* fw     = (__hip_bfloat16*)(ws + 0);         // 15,360,000
    __hip_bfloat16* ft     = (__hip_bfloat16*)(ws + 15360000);  // 262,144
    __hip_bfloat16* wbt    = (__hip_bfloat16*)(ws + 15622144);  // 131,072
    __hip_bfloat16* wbd    = (__hip_bfloat16*)(ws + 15753216);  // 131,072
    __hip_bfloat16* wbtd   = (__hip_bfloat16*)(ws + 15884288);  // 131,072 -> 16,015,360
    __hip_bfloat16* agg_wd = (__hip_bfloat16*)(ws + 16015360);  // 5,120,000 (bf16)
    __hip_bfloat16* agg_td = (__hip_bfloat16*)(ws + 21135360);  // 5,120,000 (bf16)
    float* part      = (float*)(ws + 26255360);                 // 16*512*256*4 = 8,388,608
    float* part_sumw = (float*)(ws + 34643968);                 // 32,768
    float* mw_wd     = (float*)(ws + 34676736);                 // 40,000
    float* mw_td     = (float*)(ws + 34716736);                 // 40,000 -> 34,756,736
    // line-padded allocator counters (1 counter per 64B line):
    int* cur_wt = (int*)(ws + 34756736);                        // 8192*64  = 524,288
    int* cur_wd = (int*)(ws + 35281024);                        // 10000*64 = 640,000
    int* cur_td = (int*)(ws + 35921024);                        // 10000*64 = 640,000 -> 36,561,024
    int2v* pk_wt = (int2v*)(ws + 36561024);                     // 8192*96*8  = 6,291,456
    int2v* pk_wd = (int2v*)(ws + 42852480);                     // 10000*72*8 = 5,760,000
    int2v* pk_td = (int2v*)(ws + 48612480);                     // 10000*48*8 = 3,840,000
    //                                                          // -> 52,452,480

    float* out = (float*)d_out;
    float* out_topic = out + (size_t)N_WORD * DIM;
    float* out_doc   = out + (size_t)(N_WORD + N_TOPIC) * DIM;

    // zero line-padded bucket allocators (contiguous 1,804,288 B)
    hipMemsetAsync(ws + 34756736, 0, 1804288, stream);

    // k1: ILP-4 capacity-bucket scatter + bf16 casts
    scatter_cast<<<SC_BLOCKS, 256, 0, stream>>>(
        wt_src, wt_dst, w_wt, wd_src, wd_dst, w_wd, td_src, td_dst, w_td,
        cur_wt, cur_wd, cur_td, pk_wt, pk_wd, pk_td,
        feat_word, feat_topic, Wt, Wd, Wtd, fw, ft, wbt, wbd, wbtd);

    // k2: paired-row gathers + word passthrough copy
    gather_all<<<GC_BLOCKS, 256, 0, stream>>>(
        fw, ft,
        pk_wt, cur_wt,
        pk_wd, cur_wd,
        pk_td, cur_td,
        part, part_sumw, agg_wd, mw_wd, agg_td, mw_td,
        feat_word, out);

    // k3: gemm with LDS-staged doc strips (A logical traffic 16x -> 1x)
    gemm_all<<<GEMM_BLOCKS, 256, 0, stream>>>(
        part, part_sumw, cur_wt,
        wbt, bt,
        agg_wd, wbd, bd, mw_wd,
        agg_td, wbtd, btd, mw_td,
        out_topic, out_doc);
}